// Round 17
// baseline (226.350 us; speedup 1.0000x reference)
//
#include <hip/hip_runtime.h>
#include <hip/hip_bf16.h>
#include <cstdint>

// Pipeline (all bf16 MFMA, fp32 accum):
//   cvt_all -> gemm1(qkv) -> transpose_v -> attn(32x32 swapped-QK^T, in-register P,
//   2-deep pair pipeline) -> gemm2(split-K x4) -> ln_sum1(+src) -> gemm3(relu)
//   -> gemm4(split-K x4) -> ln_sum2(+x_bf)
// Round-17: attn pair body reordered (T15): QK(t0), vb(t0), QK(t1), vb(t1), then
// SM(t0), PV(t0), SM(t1), PV(t1) — t0's softmax VALU overlaps t1's QK MFMAs,
// PV(t0) covers SM(t1). Static 2-state (named, compile-time indices). Barrier/
// ring/staging and all other kernels byte-identical to round 16.

using bf16 = __hip_bfloat16;
typedef __attribute__((ext_vector_type(8))) __bf16 bf16x8;
typedef __attribute__((ext_vector_type(4))) __bf16 bf16x4;
typedef __attribute__((ext_vector_type(4))) float f32x4;
typedef __attribute__((ext_vector_type(16))) float f32x16;

__device__ __forceinline__ void gload_lds16(const void* g, void* l) {
    auto gp = (const __attribute__((address_space(1))) void*)(uintptr_t)g;
    auto lp = (__attribute__((address_space(3))) void*)(uint32_t)(uintptr_t)l;
    __builtin_amdgcn_global_load_lds(gp, lp, 16, 0, 0);
}

// raw v_exp_f32 (1 instr) — scores are small/finite, no guard path needed
__device__ __forceinline__ float fast_exp2(float x) {
#if __has_builtin(__builtin_amdgcn_exp2f)
    return __builtin_amdgcn_exp2f(x);
#else
    float r;
    asm("v_exp_f32 %0, %1" : "=v"(r) : "v"(x));
    return r;
#endif
}

// 2-instr f32->bf16 (round-to-nearest). Inputs finite; bias far below threshold.
__device__ __forceinline__ bf16 bf16_rn(float x) {
    uint32_t u = __builtin_bit_cast(uint32_t, x);
    uint16_t h = (uint16_t)((u + 0x8000u) >> 16);
    return __builtin_bit_cast(bf16, h);
}

__device__ __forceinline__ float bf2f(__bf16 x) {
    return (float)x;
}

// pack two f32 -> u32 of 2 bf16 (lo = a, hi = b)
__device__ __forceinline__ unsigned cvt_pk_bf16(float a, float b) {
    unsigned r;
    asm("v_cvt_pk_bf16_f32 %0, %1, %2" : "=v"(r) : "v"(a), "v"(b));
    return r;
}

// v_permlane32_swap_b32: new_a[l>=32] = old_b[l-32]; new_b[l<32] = old_a[l+32]
__device__ __forceinline__ void pl32swap(unsigned& a, unsigned& b) {
    asm volatile("v_permlane32_swap_b32 %0, %1" : "+v"(a), "+v"(b));
}

// ---------------- GEMM: C[M,N] = A[M,K] * B[N,K]^T (+bias, epilogue) ----------------
// EPI 0: qkv -> bf16, cols < 1024 scaled by d^-0.5 * log2(e)
// EPI 2: bf16 out = relu(acc + bias)
// EPI 3: split-K partial (gridDim.z=Z): slice z covers K columns [z*K, z*K+K) of
//        A/B (row stride lda), writes bf16 partial to Cb + z*M*N; z=0 adds bias.
template <int EPI>
__global__ __launch_bounds__(256, 2) void gemm_bt(
    const bf16* __restrict__ A, const bf16* __restrict__ B,
    const float* __restrict__ bias, bf16* __restrict__ Cb,
    int M, int N, int K, int lda) {
    __shared__ alignas(16) bf16 As[128 * 32];
    __shared__ alignas(16) bf16 Bs[128 * 32];

    const int tid = threadIdx.x;
    const int wid = tid >> 6;
    const int lane = tid & 63;
    const int g = lane >> 4;
    const int li = lane & 15;

    if (EPI == 3) {
        const int zo = blockIdx.z * K;
        A += zo;
        B += zo;
    }

    // XCD-aware bijective swizzle (all grids here have nwg % 8 == 0)
    int wg = blockIdx.y * gridDim.x + blockIdx.x;
    const int nwg = gridDim.x * gridDim.y;
    const int cpx = nwg >> 3;
    wg = (wg & 7) * cpx + (wg >> 3);
    const int bx = wg % (int)gridDim.x;
    const int by = wg / (int)gridDim.x;

    const int row0 = by * 128;
    const int col0 = bx * 128;
    const int wr = (wid >> 1) * 64;
    const int wc = (wid & 1) * 64;

    const int c0 = wid, c1 = wid + 4;
    const int srow = lane >> 2;
    const int scol = (lane & 3) * 8;

    const bf16* Ag0 = A + (size_t)(row0 + c0 * 16 + srow) * lda + scol;
    const bf16* Ag1 = A + (size_t)(row0 + c1 * 16 + srow) * lda + scol;
    const bf16* Bg0 = B + (size_t)(col0 + c0 * 16 + srow) * lda + scol;
    const bf16* Bg1 = B + (size_t)(col0 + c1 * 16 + srow) * lda + scol;

    bf16* lA0 = &As[c0 * 512];
    bf16* lA1 = &As[c1 * 512];
    bf16* lB0 = &Bs[c0 * 512];
    bf16* lB1 = &Bs[c1 * 512];

    f32x4 acc[4][4];
#pragma unroll
    for (int i = 0; i < 4; ++i)
#pragma unroll
        for (int j = 0; j < 4; ++j) acc[i][j] = (f32x4){0.f, 0.f, 0.f, 0.f};

    for (int k0 = 0; k0 < K; k0 += 32) {
        gload_lds16(Ag0 + k0, lA0);
        gload_lds16(Ag1 + k0, lA1);
        gload_lds16(Bg0 + k0, lB0);
        gload_lds16(Bg1 + k0, lB1);
        __syncthreads();

        bf16x8 af[4], bfr[4];
#pragma unroll
        for (int i = 0; i < 4; ++i) {
            af[i] = *(const bf16x8*)&As[(wr + i * 16 + li) * 32 + g * 8];
            bfr[i] = *(const bf16x8*)&Bs[(wc + i * 16 + li) * 32 + g * 8];
        }
#pragma unroll
        for (int i = 0; i < 4; ++i)
#pragma unroll
            for (int j = 0; j < 4; ++j)
                acc[i][j] = __builtin_amdgcn_mfma_f32_16x16x32_bf16(af[i], bfr[j], acc[i][j], 0, 0, 0);
        __syncthreads();
    }

#pragma unroll
    for (int i = 0; i < 4; ++i) {
#pragma unroll
        for (int j = 0; j < 4; ++j) {
            const int col = col0 + wc + j * 16 + li;
            const float bv = (EPI == 3 && blockIdx.z != 0) ? 0.f : bias[col];
#pragma unroll
            for (int r = 0; r < 4; ++r) {
                const int row = row0 + wr + i * 16 + g * 4 + r;
                const size_t idx = (size_t)row * N + col;
                float v = acc[i][j][r] + bv;
                if (EPI == 0) {
                    if (col < 1024) v *= 0.18033688011112042f;  // d^-0.5 * log2(e)
                    Cb[idx] = bf16_rn(v);
                } else if (EPI == 2) {
                    Cb[idx] = bf16_rn(v > 0.f ? v : 0.f);
                } else {  // EPI == 3
                    Cb[(size_t)blockIdx.z * ((size_t)M * N) + idx] = bf16_rn(v);
                }
            }
        }
    }
}

// ---------------- V transpose: VT[(b*16+h)*64 + d][s] for s in [0,2080) ----------------
__global__ __launch_bounds__(256) void transpose_v(const bf16* __restrict__ qkv,
                                                   const bf16* __restrict__ mv,
                                                   bf16* __restrict__ vt) {
    __shared__ bf16 tile[64][72];
    const int t = blockIdx.x;  // 0..32 (32 = mem-token tile, 32 rows)
    const int h = blockIdx.y;
    const int b = blockIdx.z;
    const int tid = threadIdx.x;
    const int r = tid >> 2;
    const int c = (tid & 3) * 16;
    const int s0 = t * 64;
    if (t < 32) {
        const bf16* p = qkv + (size_t)((s0 + r) * 2 + b) * 3072 + 2048 + h * 64 + c;
        *(bf16x8*)&tile[r][c] = *(const bf16x8*)p;
        *(bf16x8*)&tile[r][c + 8] = *(const bf16x8*)(p + 8);
    } else if (r < 32) {
        const bf16* p = mv + (size_t)r * 1024 + h * 64 + c;
        *(bf16x8*)&tile[r][c] = *(const bf16x8*)p;
        *(bf16x8*)&tile[r][c + 8] = *(const bf16x8*)(p + 8);
    }
    __syncthreads();
    const int d = tid >> 2;
    const int sc = (tid & 3) * 16;
    const int smax = (t < 32) ? 64 : 32;
    if (sc < smax) {
        bf16 tmp[16];
#pragma unroll
        for (int j = 0; j < 16; ++j) tmp[j] = tile[sc + j][d];
        bf16* q = vt + (size_t)((b * 16 + h) * 64 + d) * 2080 + s0 + sc;
        *(bf16x8*)q = *(const bf16x8*)&tmp[0];
        *(bf16x8*)(q + 8) = *(const bf16x8*)&tmp[8];
    }
}

// ---------------- flash attention (32x32 swapped-QK^T, in-register P, T15 pair) --------
// Block = 4 waves x 32 q-rows. Grid (h, qtile, b): x=16 % 8 == 0 -> all blocks of
// head h share XCD h%8, K/V L2-resident. 4-slot K/V ring, barrier every 2 tiles.
// Pair body reordered: QK(t0), vb(t0), QK(t1), vb(t1), SM(t0), PV(t0), SM(t1), PV(t1)
// so softmax VALU overlaps the other tile's MFMA clusters.
__global__ __launch_bounds__(256, 2) void attn_kernel(
    const bf16* __restrict__ qkv, const bf16* __restrict__ mk,
    const bf16* __restrict__ vt, bf16* __restrict__ ctx) {
    __shared__ alignas(16) bf16 Kst[4][64 * 64];
    __shared__ alignas(16) bf16 Vst[4][64 * 64];

    const int tid = threadIdx.x;
    const int wid = tid >> 6;
    const int lane = tid & 63;
    const int l31 = lane & 31;
    const int hh = lane >> 5;
    const int l7 = lane & 7;

    const int h = blockIdx.x;
    const int b = blockIdx.z;
    const int q0 = blockIdx.y * 128 + wid * 32;

    const bf16* vth = vt + (size_t)((b * 16 + h) * 64) * 2080;

    const int srow8 = lane >> 3;           // row & 7
    const int sslot = (lane & 7) ^ srow8;  // swizzled 16B slot in the row

#define STAGE_KV(buf, t)                                                                       \
    {                                                                                          \
        const int _s0 = (t) * 64;                                                              \
        _Pragma("unroll") for (int j = 0; j < 2; ++j) {                                        \
            const int rw = (wid * 2 + j) * 8 + srow8;                                          \
            gload_lds16(qkv + (size_t)((_s0 + rw) * 2 + b) * 3072 + 1024 + h * 64 + sslot * 8, \
                        &Kst[buf][(wid * 2 + j) * 512]);                                       \
            gload_lds16(vth + (size_t)rw * 2080 + _s0 + sslot * 8,                             \
                        &Vst[buf][(wid * 2 + j) * 512]);                                       \
        }                                                                                      \
    }

    // Q as 32x32 B-operand: qf[dc] = Q[q0+l31][h*64 + dc*16 + hh*8 .. +7]
    bf16x8 qf[4];
#pragma unroll
    for (int dc = 0; dc < 4; ++dc)
        qf[dc] = *(const bf16x8*)(qkv + (size_t)((q0 + l31) * 2 + b) * 3072 + h * 64 + dc * 16 +
                                  hh * 8);

    f32x16 zero16;
#pragma unroll
    for (int i = 0; i < 16; ++i) zero16[i] = 0.f;

    f32x16 o[2];
    o[0] = zero16;
    o[1] = zero16;
    float lrow = 0.f;

    STAGE_KV(0, 0);
    STAGE_KV(1, 1);

    for (int tp = 0; tp < 16; ++tp) {
        const int t0 = tp * 2;
        __syncthreads();  // ring slots staged; prior readers done
        if (t0 + 2 < 32) STAGE_KV((t0 + 2) & 3, t0 + 2);
        if (t0 + 3 < 32) STAGE_KV((t0 + 3) & 3, t0 + 3);

        const int cur0 = t0 & 3;
        const int cur1 = (t0 + 1) & 3;
        const bf16* kb0 = &Kst[cur0][0];
        const bf16* vb0p = &Vst[cur0][0];
        const bf16* kb1 = &Kst[cur1][0];
        const bf16* vb1p = &Vst[cur1][0];

        // ---- QK(t0) ----
        f32x16 sa0[2];
        sa0[0] = zero16;
        sa0[1] = zero16;
        __builtin_amdgcn_s_setprio(1);
#pragma unroll
        for (int dc = 0; dc < 4; ++dc)
#pragma unroll
            for (int kb = 0; kb < 2; ++kb) {
                const bf16x8 ka =
                    *(const bf16x8*)&kb0[(kb * 32 + l31) * 64 + (((dc * 2 + hh) ^ l7) * 8)];
                sa0[kb] = __builtin_amdgcn_mfma_f32_32x32x16_bf16(ka, qf[dc], sa0[kb], 0, 0, 0);
            }
        __builtin_amdgcn_s_setprio(0);

        // ---- vb(t0) reads (in flight under QK(t1)) ----
        bf16x8 vbr0[4][2];
#pragma unroll
        for (int kc = 0; kc < 4; ++kc)
#pragma unroll
            for (int dt = 0; dt < 2; ++dt)
                vbr0[kc][dt] =
                    *(const bf16x8*)&vb0p[(dt * 32 + l31) * 64 + (((kc * 2 + hh) ^ l7) * 8)];

        // ---- QK(t1) ----
        f32x16 sa1[2];
        sa1[0] = zero16;
        sa1[1] = zero16;
        __builtin_amdgcn_s_setprio(1);
#pragma unroll
        for (int dc = 0; dc < 4; ++dc)
#pragma unroll
            for (int kb = 0; kb < 2; ++kb) {
                const bf16x8 ka =
                    *(const bf16x8*)&kb1[(kb * 32 + l31) * 64 + (((dc * 2 + hh) ^ l7) * 8)];
                sa1[kb] = __builtin_amdgcn_mfma_f32_32x32x16_bf16(ka, qf[dc], sa1[kb], 0, 0, 0);
            }
        __builtin_amdgcn_s_setprio(0);

        // ---- vb(t1) reads ----
        bf16x8 vbr1[4][2];
#pragma unroll
        for (int kc = 0; kc < 4; ++kc)
#pragma unroll
            for (int dt = 0; dt < 2; ++dt)
                vbr1[kc][dt] =
                    *(const bf16x8*)&vb1p[(dt * 32 + l31) * 64 + (((kc * 2 + hh) ^ l7) * 8)];

        // ---- SM(t0): overlaps QK(t1) MFMA drain ----
        unsigned pk0[2][8];
#pragma unroll
        for (int kb = 0; kb < 2; ++kb)
#pragma unroll
            for (int m = 0; m < 8; ++m) {
                const float p0 = fast_exp2(sa0[kb][2 * m]);
                const float p1 = fast_exp2(sa0[kb][2 * m + 1]);
                lrow += p0 + p1;
                pk0[kb][m] = cvt_pk_bf16(p0, p1);
            }

        // ---- PV(t0) ----
        __builtin_amdgcn_s_setprio(1);
#pragma unroll
        for (int kc = 0; kc < 4; ++kc) {
            const int kb = kc >> 1;
            const int base = (kc & 1) * 4;
            unsigned A0 = pk0[kb][base], A1 = pk0[kb][base + 2];
            unsigned B0 = pk0[kb][base + 1], B1 = pk0[kb][base + 3];
            pl32swap(A0, A1);
            pl32swap(B0, B1);
            union {
                unsigned u[4];
                bf16x8 v;
            } pa;
            pa.u[0] = A0;
            pa.u[1] = B0;
            pa.u[2] = A1;
            pa.u[3] = B1;
#pragma unroll
            for (int dt = 0; dt < 2; ++dt)
                o[dt] = __builtin_amdgcn_mfma_f32_32x32x16_bf16(pa.v, vbr0[kc][dt], o[dt], 0, 0, 0);
        }
        __builtin_amdgcn_s_setprio(0);

        // ---- SM(t1): overlaps PV(t0) MFMA drain ----
        unsigned pk1[2][8];
#pragma unroll
        for (int kb = 0; kb < 2; ++kb)
#pragma unroll
            for (int m = 0; m < 8; ++m) {
                const float p0 = fast_exp2(sa1[kb][2 * m]);
                const float p1 = fast_exp2(sa1[kb][2 * m + 1]);
                lrow += p0 + p1;
                pk1[kb][m] = cvt_pk_bf16(p0, p1);
            }

        // ---- PV(t1) ----
        __builtin_amdgcn_s_setprio(1);
#pragma unroll
        for (int kc = 0; kc < 4; ++kc) {
            const int kb = kc >> 1;
            const int base = (kc & 1) * 4;
            unsigned A0 = pk1[kb][base], A1 = pk1[kb][base + 2];
            unsigned B0 = pk1[kb][base + 1], B1 = pk1[kb][base + 3];
            pl32swap(A0, A1);
            pl32swap(B0, B1);
            union {
                unsigned u[4];
                bf16x8 v;
            } pa;
            pa.u[0] = A0;
            pa.u[1] = B0;
            pa.u[2] = A1;
            pa.u[3] = B1;
#pragma unroll
            for (int dt = 0; dt < 2; ++dt)
                o[dt] = __builtin_amdgcn_mfma_f32_32x32x16_bf16(pa.v, vbr1[kc][dt], o[dt], 0, 0, 0);
        }
        __builtin_amdgcn_s_setprio(0);
    }

    // ---- tail: 32 memory tokens (global reads, no LDS staging) ----
    {
        f32x16 sat = zero16;
#pragma unroll
        for (int dc = 0; dc < 4; ++dc) {
            const bf16x8 ka =
                *(const bf16x8*)(mk + (size_t)l31 * 1024 + h * 64 + dc * 16 + hh * 8);
            sat = __builtin_amdgcn_mfma_f32_32x32x16_bf16(ka, qf[dc], sat, 0, 0, 0);
        }
        unsigned pkt[8];
#pragma unroll
        for (int m = 0; m < 8; ++m) {
            const float p0 = fast_exp2(sat[2 * m]);
            const float p1 = fast_exp2(sat[2 * m + 1]);
            lrow += p0 + p1;
            pkt[m] = cvt_pk_bf16(p0, p1);
        }
#pragma unroll
        for (int kc = 0; kc < 2; ++kc) {
            const int base = kc * 4;
            unsigned A0 = pkt[base], A1 = pkt[base + 2];
            unsigned B0 = pkt[base + 1], B1 = pkt[base + 3];
            pl32swap(A0, A1);
            pl32swap(B0, B1);
            union {
                unsigned u[4];
                bf16x8 v;
            } pa;
            pa.u[0] = A0;
            pa.u[1] = B0;
            pa.u[2] = A1;
            pa.u[3] = B1;
#pragma unroll
            for (int dt = 0; dt < 2; ++dt) {
                const bf16x8 vb = *(const bf16x8*)(vth + (size_t)(dt * 32 + l31) * 2080 + 2048 +
                                                   kc * 16 + hh * 8);
                o[dt] = __builtin_amdgcn_mfma_f32_32x32x16_bf16(pa.v, vb, o[dt], 0, 0, 0);
            }
        }
    }

    // epilogue: lanes l and l^32 share q=l31 and split k — combine, then
    // redistribute 1/sum to the lanes holding each output row.
    const float ssum = lrow + __shfl_xor(lrow, 32);
    const float inv_own = 1.f / ssum;
#pragma unroll
    for (int r = 0; r < 16; ++r) {
        const int qr = (r & 3) + 8 * (r >> 2) + 4 * hh;
        const float iv = __shfl(inv_own, qr);
#pragma unroll
        for (int dt = 0; dt < 2; ++dt)
            ctx[(size_t)((q0 + qr) * 2 + b) * 1024 + h * 64 + dt * 32 + l31] =
                bf16_rn(o[dt][r] * iv);
    }
#undef STAGE_KV
}

// ---------------- LayerNorm over rows of 1024: y = LN(p0+p1+p2+p3 + res) ----------------
// pbase: 4 bf16 split-K partials at stride 4096*1024 (p0 carries the bias).
// Residual: resf (fp32) or resb (bf16) — exactly one non-null.
__global__ __launch_bounds__(256, 4) void ln_sum_kernel(
    const bf16* __restrict__ pbase, const float* __restrict__ resf,
    const bf16* __restrict__ resb, const float* __restrict__ gw, const float* __restrict__ bw,
    float* __restrict__ y, bf16* __restrict__ ybf) {
    const int row = blockIdx.x;
    const int tid = threadIdx.x;
    const size_t base = (size_t)row * 1024 + tid * 4;
    const size_t PS = (size_t)4096 * 1024;

    float4 v = {0.f, 0.f, 0.f, 0.f};
#pragma unroll
    for (int z = 0; z < 4; ++z) {
        const bf16x4 a = *(const bf16x4*)(pbase + z * PS + base);
        v.x += bf2f(a[0]);
        v.y += bf2f(a[1]);
        v.z += bf2f(a[2]);
        v.w += bf2f(a[3]);
    }
    if (resf) {
        const float4 xr = ((const float4*)(resf + (size_t)row * 1024))[tid];
        v.x += xr.x; v.y += xr.y; v.z += xr.z; v.w += xr.w;
    } else {
        const bf16x4 xr = *(const bf16x4*)(resb + base);
        v.x += bf2f(xr[0]); v.y += bf2f(xr[1]); v.z += bf2f(xr[2]); v.w += bf2f(xr[3]);
    }

    float s = v.x + v.y + v.z + v.w;
    float s2 = v.x * v.x + v.y * v.y + v.z * v.z + v.w * v.w;
#pragma unroll
    for (int d = 1; d < 64; d <<= 1) {
        s += __shfl_xor(s, d);
        s2 += __shfl_xor(s2, d);
    }
    __shared__ float red[8];
    const int wid = tid >> 6, lane = tid & 63;
    if (lane == 0) { red[wid] = s; red[4 + wid] = s2; }
    __syncthreads();
    s = red[0] + red[1] + red[2] + red[3];
    s2 = red[4] + red[5] + red[6] + red[7];
    const float mu = s * (1.f / 1024.f);
    const float var = s2 * (1.f / 1024.f) - mu * mu;
    const float rstd = rsqrtf(var + 1e-5f);
    const float4 gv = ((const float4*)gw)[tid];
    const float4 bv = ((const float4*)bw)[tid];
    float4 out;
    out.x = (v.x - mu) * rstd * gv.x + bv.x;
    out.y = (v.y - mu) * rstd * gv.y + bv.y;
    out.z = (v.z - mu) * rstd * gv.z + bv.z;
    out.w = (v.w - mu) * rstd * gv.w + bv.w;
    if (y) ((float4*)(y + (size_t)row * 1024))[tid] = out;
    if (ybf) {
        bf16* yb = ybf + base;
        yb[0] = bf16_rn(out.x);
        yb[1] = bf16_rn(out.y);
        yb[2] = bf16_rn(out.z);
        yb[3] = bf16_rn(out.w);
    }
}

// ---------------- fused fp32 -> bf16 for all 7 inputs (one launch) ----------------
// f4-cumulative segment bounds (src, inproj_w, outw, w1, w2, memk, memv):
//   1048576, 1835008, 2097152, 3145728, 4194304, 4202496, 4210688 (= 16448*256 exactly)
__global__ void cvt_all_kernel(const float* __restrict__ s0, const float* __restrict__ s1,
                               const float* __restrict__ s2, const float* __restrict__ s3,
                               const float* __restrict__ s4, const float* __restrict__ s5,
                               const float* __restrict__ s6, bf16* __restrict__ d0,
                               bf16* __restrict__ d1, bf16* __restrict__ d2, bf16* __restrict__ d3,
                               bf16* __restrict__ d4, bf16* __restrict__ d5, bf16* __restrict__ d6) {
    int i = blockIdx.x * 256 + threadIdx.x;
    const float* in;
    bf16* out;
    float scale = 1.f;
    if (i < 1048576) {
        in = s0; out = d0;
    } else if (i < 1835008) {
        in = s1; out = d1; i -= 1048576;
    } else if (i < 2097152) {
        in = s2; out = d2; i -= 1835008;
    } else if (i < 3145728) {
        in = s3; out = d3; i -= 2097152;
    } else if (i < 4194304) {
        in = s4; out = d4; i -= 3145728;
    } else if (i < 4202496) {
        in = s5; out = d5; i -= 4194304; scale = 8.f;  // memk * d^0.5 (log2e rides on q)
    } else {
        in = s6; out = d6; i -= 4202496; scale = 5.656854249492381f;  // memv * M^0.5
    }
    const float4 v = ((const float4*)in)[i];
    bf16* op = out + (size_t)i * 4;
    op[0] = bf16_rn(v.x * scale);
    op[1] = bf16_rn(v.y * scale);
    op[2] = bf16_rn(v.z * scale);
    op[3] = bf16_rn(v.w * scale);
}

extern "C" void kernel_launch(void* const* d_in, const int* in_sizes, int n_in, void* d_out,
                              int out_size, void* d_ws, size_t ws_size, hipStream_t stream) {
    const float* src = (const float*)d_in[0];
    const float* inproj_w = (const float*)d_in[1];
    const float* inproj_b = (const float*)d_in[2];
    const float* outw = (const float*)d_in[3];
    const float* outb = (const float*)d_in[4];
    const float* memk = (const float*)d_in[5];
    const float* memv = (const float*)d_in[6];
    const float* w1 = (const float*)d_in[7];
    const float* b1 = (const float*)d_in[8];
    const float* w2 = (const float*)d_in[9];
    const float* b2 = (const float*)d_in[10];
    const float* ln1g = (const float*)d_in[11];
    const float* ln1b = (const float*)d_in[12];
    const float* ln2g = (const float*)d_in[13];
    const float* ln2b = (const float*)d_in[14];

    char* ws = (char*)d_ws;
    const size_t MB = 1024 * 1024;
    // Live-range plan (ws <= 97 MB):
    //   0..24   weights bf16 (inproj 6 | outw 2 | w1 8 | w2 8)
    //   24..25  mk_bf, mv_bf
    //   25..33  src_bf -> ctx (attn out) -> x_bf (ln1 out)
    //   33..65  qkv (gemm1 out) -> gemm2 partials (qkv dead) -> h (gemm3 out)
    //   65..97  vt (8.5MB, transpose_v -> attn) -> gemm4 partials (vt dead)
    bf16* w_inproj_bf = (bf16*)(ws + 0);
    bf16* w_out_bf = (bf16*)(ws + 6 * MB);
    bf16* w1_bf = (bf16*)(ws + 8 * MB);
    bf16* w2_bf = (bf16*)(ws + 16 * MB);
    bf16* mk_bf = (bf16*)(ws + 24 * MB);
    bf16* mv_bf = (bf16*)(ws + 24 * MB + 65536);
    bf16* src_bf = (bf16*)(ws + 25 * MB);
    bf16* ctx_bf = src_bf;     // attn out (src_bf dead after gemm1)
    bf16* x_bf = src_bf;       // ln1 out (ctx dead after gemm2)
    bf16* qkv_bf = (bf16*)(ws + 33 * MB);
    bf16* g2p = qkv_bf;        // gemm2 partials 4x8MB (qkv dead after attn)
    bf16* h_bf = qkv_bf;       // gemm3 out (partials dead after ln_sum1)
    bf16* vt_bf = (bf16*)(ws + 65 * MB);
    bf16* g4p = vt_bf;         // gemm4 partials 4x8MB (vt dead after attn)
    float* outp = (float*)d_out;

    // one fused conversion launch (16448 * 256 threads == total f4 count exactly)
    cvt_all_kernel<<<dim3(16448), dim3(256), 0, stream>>>(
        src, inproj_w, outw, w1, w2, memk, memv,
        src_bf, w_inproj_bf, w_out_bf, w1_bf, w2_bf, mk_bf, mv_bf);

    // qkv = src @ in_proj_w^T + b  (q scaled by d^-0.5*log2e)
    gemm_bt<0><<<dim3(3072 / 128, 4096 / 128), 256, 0, stream>>>(
        src_bf, w_inproj_bf, inproj_b, qkv_bf, 4096, 3072, 1024, 1024);
    // VT = V^T (incl. mem tokens)
    transpose_v<<<dim3(33, 16, 2), 256, 0, stream>>>(qkv_bf, mv_bf, vt_bf);
    // ctx = softmax(q k^T) v    (grid: x=head for XCD L2 locality; 512 blocks)
    attn_kernel<<<dim3(16, 16, 2), 256, 0, stream>>>(qkv_bf, mk_bf, vt_bf, ctx_bf);
    // gemm2 split-K x4: partials = ctx @ out_w^T (+out_b on z=0), K=256 each
    gemm_bt<3><<<dim3(1024 / 128, 4096 / 128, 4), 256, 0, stream>>>(
        ctx_bf, w_out_bf, outb, g2p, 4096, 1024, 256, 1024);
    // x = LN1(p0..p3 + src)  -> bf16 only
    ln_sum_kernel<<<dim3(4096), 256, 0, stream>>>(g2p, src, nullptr, ln1g, ln1b, nullptr, x_bf);
    // h = relu(x @ w1^T + b1)
    gemm_bt<2><<<dim3(4096 / 128, 4096 / 128), 256, 0, stream>>>(
        x_bf, w1_bf, b1, h_bf, 4096, 4096, 1024, 1024);
    // gemm4 split-K x4: partials = h @ w2^T (+b2 on z=0), K=1024 each
    gemm_bt<3><<<dim3(1024 / 128, 4096 / 128, 4), 256, 0, stream>>>(
        h_bf, w2_bf, b2, g4p, 4096, 1024, 1024, 4096);
    // out = LN2(p0..p3 + x)
    ln_sum_kernel<<<dim3(4096), 256, 0, stream>>>(g4p, nullptr, x_bf, ln2g, ln2b, outp, nullptr);
}

// Round 18
// 225.333 us; speedup vs baseline: 1.0045x; 1.0045x over previous
//
#include <hip/hip_runtime.h>
#include <hip/hip_bf16.h>
#include <cstdint>

// Pipeline (all bf16 MFMA, fp32 accum):
//   cvt_all -> gemm1(qkv) -> transpose_v -> attn(32x32 swapped-QK^T, in-register P)
//   -> gemm2(split-K x4) -> ln_sum1(+src) -> gemm3(relu) -> gemm4(split-K x4) -> ln_sum2(+x_bf)
// Round-18: (a) revert round-17's T15 pair reorder (regressed: 52.0->53.3us, m253
// confirms T15 doesn't transfer to MFMA/VALU loops); (b) row-sums moved to the
// MFMA pipe: lsum = mfma(pa, ones) per k-chunk replaces 32 VALU adds/tile AND the
// epilogue shfl dance (lsum[r] lands in o's exact row mapping). VALU -29%/tile.
// All non-attn kernels byte-identical to round 16.

using bf16 = __hip_bfloat16;
typedef __attribute__((ext_vector_type(8))) __bf16 bf16x8;
typedef __attribute__((ext_vector_type(4))) __bf16 bf16x4;
typedef __attribute__((ext_vector_type(4))) float f32x4;
typedef __attribute__((ext_vector_type(16))) float f32x16;

__device__ __forceinline__ void gload_lds16(const void* g, void* l) {
    auto gp = (const __attribute__((address_space(1))) void*)(uintptr_t)g;
    auto lp = (__attribute__((address_space(3))) void*)(uint32_t)(uintptr_t)l;
    __builtin_amdgcn_global_load_lds(gp, lp, 16, 0, 0);
}

// raw v_exp_f32 (1 instr) — scores are small/finite, no guard path needed
__device__ __forceinline__ float fast_exp2(float x) {
#if __has_builtin(__builtin_amdgcn_exp2f)
    return __builtin_amdgcn_exp2f(x);
#else
    float r;
    asm("v_exp_f32 %0, %1" : "=v"(r) : "v"(x));
    return r;
#endif
}

// 2-instr f32->bf16 (round-to-nearest). Inputs finite; bias far below threshold.
__device__ __forceinline__ bf16 bf16_rn(float x) {
    uint32_t u = __builtin_bit_cast(uint32_t, x);
    uint16_t h = (uint16_t)((u + 0x8000u) >> 16);
    return __builtin_bit_cast(bf16, h);
}

__device__ __forceinline__ float bf2f(__bf16 x) {
    return (float)x;
}

// pack two f32 -> u32 of 2 bf16 (lo = a, hi = b)
__device__ __forceinline__ unsigned cvt_pk_bf16(float a, float b) {
    unsigned r;
    asm("v_cvt_pk_bf16_f32 %0, %1, %2" : "=v"(r) : "v"(a), "v"(b));
    return r;
}

// v_permlane32_swap_b32: new_a[l>=32] = old_b[l-32]; new_b[l<32] = old_a[l+32]
__device__ __forceinline__ void pl32swap(unsigned& a, unsigned& b) {
    asm volatile("v_permlane32_swap_b32 %0, %1" : "+v"(a), "+v"(b));
}

// ---------------- GEMM: C[M,N] = A[M,K] * B[N,K]^T (+bias, epilogue) ----------------
// EPI 0: qkv -> bf16, cols < 1024 scaled by d^-0.5 * log2(e)
// EPI 2: bf16 out = relu(acc + bias)
// EPI 3: split-K partial (gridDim.z=Z): slice z covers K columns [z*K, z*K+K) of
//        A/B (row stride lda), writes bf16 partial to Cb + z*M*N; z=0 adds bias.
template <int EPI>
__global__ __launch_bounds__(256, 2) void gemm_bt(
    const bf16* __restrict__ A, const bf16* __restrict__ B,
    const float* __restrict__ bias, bf16* __restrict__ Cb,
    int M, int N, int K, int lda) {
    __shared__ alignas(16) bf16 As[128 * 32];
    __shared__ alignas(16) bf16 Bs[128 * 32];

    const int tid = threadIdx.x;
    const int wid = tid >> 6;
    const int lane = tid & 63;
    const int g = lane >> 4;
    const int li = lane & 15;

    if (EPI == 3) {
        const int zo = blockIdx.z * K;
        A += zo;
        B += zo;
    }

    // XCD-aware bijective swizzle (all grids here have nwg % 8 == 0)
    int wg = blockIdx.y * gridDim.x + blockIdx.x;
    const int nwg = gridDim.x * gridDim.y;
    const int cpx = nwg >> 3;
    wg = (wg & 7) * cpx + (wg >> 3);
    const int bx = wg % (int)gridDim.x;
    const int by = wg / (int)gridDim.x;

    const int row0 = by * 128;
    const int col0 = bx * 128;
    const int wr = (wid >> 1) * 64;
    const int wc = (wid & 1) * 64;

    const int c0 = wid, c1 = wid + 4;
    const int srow = lane >> 2;
    const int scol = (lane & 3) * 8;

    const bf16* Ag0 = A + (size_t)(row0 + c0 * 16 + srow) * lda + scol;
    const bf16* Ag1 = A + (size_t)(row0 + c1 * 16 + srow) * lda + scol;
    const bf16* Bg0 = B + (size_t)(col0 + c0 * 16 + srow) * lda + scol;
    const bf16* Bg1 = B + (size_t)(col0 + c1 * 16 + srow) * lda + scol;

    bf16* lA0 = &As[c0 * 512];
    bf16* lA1 = &As[c1 * 512];
    bf16* lB0 = &Bs[c0 * 512];
    bf16* lB1 = &Bs[c1 * 512];

    f32x4 acc[4][4];
#pragma unroll
    for (int i = 0; i < 4; ++i)
#pragma unroll
        for (int j = 0; j < 4; ++j) acc[i][j] = (f32x4){0.f, 0.f, 0.f, 0.f};

    for (int k0 = 0; k0 < K; k0 += 32) {
        gload_lds16(Ag0 + k0, lA0);
        gload_lds16(Ag1 + k0, lA1);
        gload_lds16(Bg0 + k0, lB0);
        gload_lds16(Bg1 + k0, lB1);
        __syncthreads();

        bf16x8 af[4], bfr[4];
#pragma unroll
        for (int i = 0; i < 4; ++i) {
            af[i] = *(const bf16x8*)&As[(wr + i * 16 + li) * 32 + g * 8];
            bfr[i] = *(const bf16x8*)&Bs[(wc + i * 16 + li) * 32 + g * 8];
        }
#pragma unroll
        for (int i = 0; i < 4; ++i)
#pragma unroll
            for (int j = 0; j < 4; ++j)
                acc[i][j] = __builtin_amdgcn_mfma_f32_16x16x32_bf16(af[i], bfr[j], acc[i][j], 0, 0, 0);
        __syncthreads();
    }

#pragma unroll
    for (int i = 0; i < 4; ++i) {
#pragma unroll
        for (int j = 0; j < 4; ++j) {
            const int col = col0 + wc + j * 16 + li;
            const float bv = (EPI == 3 && blockIdx.z != 0) ? 0.f : bias[col];
#pragma unroll
            for (int r = 0; r < 4; ++r) {
                const int row = row0 + wr + i * 16 + g * 4 + r;
                const size_t idx = (size_t)row * N + col;
                float v = acc[i][j][r] + bv;
                if (EPI == 0) {
                    if (col < 1024) v *= 0.18033688011112042f;  // d^-0.5 * log2(e)
                    Cb[idx] = bf16_rn(v);
                } else if (EPI == 2) {
                    Cb[idx] = bf16_rn(v > 0.f ? v : 0.f);
                } else {  // EPI == 3
                    Cb[(size_t)blockIdx.z * ((size_t)M * N) + idx] = bf16_rn(v);
                }
            }
        }
    }
}

// ---------------- V transpose: VT[(b*16+h)*64 + d][s] for s in [0,2080) ----------------
__global__ __launch_bounds__(256) void transpose_v(const bf16* __restrict__ qkv,
                                                   const bf16* __restrict__ mv,
                                                   bf16* __restrict__ vt) {
    __shared__ bf16 tile[64][72];
    const int t = blockIdx.x;  // 0..32 (32 = mem-token tile, 32 rows)
    const int h = blockIdx.y;
    const int b = blockIdx.z;
    const int tid = threadIdx.x;
    const int r = tid >> 2;
    const int c = (tid & 3) * 16;
    const int s0 = t * 64;
    if (t < 32) {
        const bf16* p = qkv + (size_t)((s0 + r) * 2 + b) * 3072 + 2048 + h * 64 + c;
        *(bf16x8*)&tile[r][c] = *(const bf16x8*)p;
        *(bf16x8*)&tile[r][c + 8] = *(const bf16x8*)(p + 8);
    } else if (r < 32) {
        const bf16* p = mv + (size_t)r * 1024 + h * 64 + c;
        *(bf16x8*)&tile[r][c] = *(const bf16x8*)p;
        *(bf16x8*)&tile[r][c + 8] = *(const bf16x8*)(p + 8);
    }
    __syncthreads();
    const int d = tid >> 2;
    const int sc = (tid & 3) * 16;
    const int smax = (t < 32) ? 64 : 32;
    if (sc < smax) {
        bf16 tmp[16];
#pragma unroll
        for (int j = 0; j < 16; ++j) tmp[j] = tile[sc + j][d];
        bf16* q = vt + (size_t)((b * 16 + h) * 64 + d) * 2080 + s0 + sc;
        *(bf16x8*)q = *(const bf16x8*)&tmp[0];
        *(bf16x8*)(q + 8) = *(const bf16x8*)&tmp[8];
    }
}

// ---------------- flash attention (32x32 swapped-QK^T, in-register P) ----------------
// Round-16 structure (4-slot K/V ring, barrier every 2 tiles, sequential tile body)
// + MFMA row-sums: lsum = mfma(pa, ones) accumulates exact row sums in o's row
// mapping; epilogue is iv = 1/lsum[r] directly (no cross-lane ops).
__global__ __launch_bounds__(256, 2) void attn_kernel(
    const bf16* __restrict__ qkv, const bf16* __restrict__ mk,
    const bf16* __restrict__ vt, bf16* __restrict__ ctx) {
    __shared__ alignas(16) bf16 Kst[4][64 * 64];
    __shared__ alignas(16) bf16 Vst[4][64 * 64];

    const int tid = threadIdx.x;
    const int wid = tid >> 6;
    const int lane = tid & 63;
    const int l31 = lane & 31;
    const int hh = lane >> 5;
    const int l7 = lane & 7;

    const int h = blockIdx.x;
    const int b = blockIdx.z;
    const int q0 = blockIdx.y * 128 + wid * 32;

    const bf16* vth = vt + (size_t)((b * 16 + h) * 64) * 2080;

    const int srow8 = lane >> 3;           // row & 7
    const int sslot = (lane & 7) ^ srow8;  // swizzled 16B slot in the row

#define STAGE_KV(buf, t)                                                                       \
    {                                                                                          \
        const int _s0 = (t) * 64;                                                              \
        _Pragma("unroll") for (int j = 0; j < 2; ++j) {                                        \
            const int rw = (wid * 2 + j) * 8 + srow8;                                          \
            gload_lds16(qkv + (size_t)((_s0 + rw) * 2 + b) * 3072 + 1024 + h * 64 + sslot * 8, \
                        &Kst[buf][(wid * 2 + j) * 512]);                                       \
            gload_lds16(vth + (size_t)rw * 2080 + _s0 + sslot * 8,                             \
                        &Vst[buf][(wid * 2 + j) * 512]);                                       \
        }                                                                                      \
    }

    // Q as 32x32 B-operand: qf[dc] = Q[q0+l31][h*64 + dc*16 + hh*8 .. +7]
    bf16x8 qf[4];
#pragma unroll
    for (int dc = 0; dc < 4; ++dc)
        qf[dc] = *(const bf16x8*)(qkv + (size_t)((q0 + l31) * 2 + b) * 3072 + h * 64 + dc * 16 +
                                  hh * 8);

    // all-ones bf16 B-operand for MFMA row-sums
    bf16x8 onesv;
#pragma unroll
    for (int i = 0; i < 8; ++i) onesv[i] = __builtin_bit_cast(__bf16, (uint16_t)0x3F80);

    f32x16 zero16;
#pragma unroll
    for (int i = 0; i < 16; ++i) zero16[i] = 0.f;

    f32x16 o[2];
    o[0] = zero16;
    o[1] = zero16;
    f32x16 lsum = zero16;  // row sums, same row mapping as o

    STAGE_KV(0, 0);
    STAGE_KV(1, 1);

    for (int tp = 0; tp < 16; ++tp) {
        const int t0 = tp * 2;
        __syncthreads();  // ring slots staged; prior readers done
        if (t0 + 2 < 32) STAGE_KV((t0 + 2) & 3, t0 + 2);
        if (t0 + 3 < 32) STAGE_KV((t0 + 3) & 3, t0 + 3);

#pragma unroll
        for (int ti = 0; ti < 2; ++ti) {
            const int cur = (t0 + ti) & 3;
            const bf16* kbase = &Kst[cur][0];
            const bf16* vbase = &Vst[cur][0];

            // S^T = K * Q^T over d=64 (4 chunks of 16), two 32-k halves
            f32x16 sa[2];
            sa[0] = zero16;
            sa[1] = zero16;
            __builtin_amdgcn_s_setprio(1);
#pragma unroll
            for (int dc = 0; dc < 4; ++dc)
#pragma unroll
                for (int kb = 0; kb < 2; ++kb) {
                    const int row = kb * 32 + l31;
                    const bf16x8 ka =
                        *(const bf16x8*)&kbase[row * 64 + (((dc * 2 + hh) ^ l7) * 8)];
                    sa[kb] = __builtin_amdgcn_mfma_f32_32x32x16_bf16(ka, qf[dc], sa[kb], 0, 0, 0);
                }
            __builtin_amdgcn_s_setprio(0);

            // exp2 + pack to bf16 pairs (row sums now on the MFMA pipe)
            unsigned pk[2][8];
#pragma unroll
            for (int kb = 0; kb < 2; ++kb)
#pragma unroll
                for (int m = 0; m < 8; ++m) {
                    const float p0 = fast_exp2(sa[kb][2 * m]);
                    const float p1 = fast_exp2(sa[kb][2 * m + 1]);
                    pk[kb][m] = cvt_pk_bf16(p0, p1);
                }

            // PV + lsum: per 16-k chunk, assemble A-frag via 2 permlane swaps
            __builtin_amdgcn_s_setprio(1);
#pragma unroll
            for (int kc = 0; kc < 4; ++kc) {
                const int kb = kc >> 1;
                const int base = (kc & 1) * 4;
                unsigned A0 = pk[kb][base], A1 = pk[kb][base + 2];
                unsigned B0 = pk[kb][base + 1], B1 = pk[kb][base + 3];
                pl32swap(A0, A1);
                pl32swap(B0, B1);
                union {
                    unsigned u[4];
                    bf16x8 v;
                } pa;
                pa.u[0] = A0;
                pa.u[1] = B0;
                pa.u[2] = A1;
                pa.u[3] = B1;
#pragma unroll
                for (int dt = 0; dt < 2; ++dt) {
                    const int row = dt * 32 + l31;
                    const bf16x8 vb =
                        *(const bf16x8*)&vbase[row * 64 + (((kc * 2 + hh) ^ l7) * 8)];
                    o[dt] = __builtin_amdgcn_mfma_f32_32x32x16_bf16(pa.v, vb, o[dt], 0, 0, 0);
                }
                lsum = __builtin_amdgcn_mfma_f32_32x32x16_bf16(pa.v, onesv, lsum, 0, 0, 0);
            }
            __builtin_amdgcn_s_setprio(0);
        }
    }

    // ---- tail: 32 memory tokens (global reads, no LDS staging) ----
    {
        f32x16 sat = zero16;
#pragma unroll
        for (int dc = 0; dc < 4; ++dc) {
            const bf16x8 ka =
                *(const bf16x8*)(mk + (size_t)l31 * 1024 + h * 64 + dc * 16 + hh * 8);
            sat = __builtin_amdgcn_mfma_f32_32x32x16_bf16(ka, qf[dc], sat, 0, 0, 0);
        }
        unsigned pkt[8];
#pragma unroll
        for (int m = 0; m < 8; ++m) {
            const float p0 = fast_exp2(sat[2 * m]);
            const float p1 = fast_exp2(sat[2 * m + 1]);
            pkt[m] = cvt_pk_bf16(p0, p1);
        }
#pragma unroll
        for (int kc = 0; kc < 2; ++kc) {
            const int base = kc * 4;
            unsigned A0 = pkt[base], A1 = pkt[base + 2];
            unsigned B0 = pkt[base + 1], B1 = pkt[base + 3];
            pl32swap(A0, A1);
            pl32swap(B0, B1);
            union {
                unsigned u[4];
                bf16x8 v;
            } pa;
            pa.u[0] = A0;
            pa.u[1] = B0;
            pa.u[2] = A1;
            pa.u[3] = B1;
#pragma unroll
            for (int dt = 0; dt < 2; ++dt) {
                const bf16x8 vb = *(const bf16x8*)(vth + (size_t)(dt * 32 + l31) * 2080 + 2048 +
                                                   kc * 16 + hh * 8);
                o[dt] = __builtin_amdgcn_mfma_f32_32x32x16_bf16(pa.v, vb, o[dt], 0, 0, 0);
            }
            lsum = __builtin_amdgcn_mfma_f32_32x32x16_bf16(pa.v, onesv, lsum, 0, 0, 0);
        }
    }

    // epilogue: lsum[r] is the full row sum for row qr (same mapping as o) — no
    // cross-lane ops needed.
#pragma unroll
    for (int r = 0; r < 16; ++r) {
        const int qr = (r & 3) + 8 * (r >> 2) + 4 * hh;
        const float iv = 1.f / lsum[r];
#pragma unroll
        for (int dt = 0; dt < 2; ++dt)
            ctx[(size_t)((q0 + qr) * 2 + b) * 1024 + h * 64 + dt * 32 + l31] =
                bf16_rn(o[dt][r] * iv);
    }
#undef STAGE_KV
}

// ---------------- LayerNorm over rows of 1024: y = LN(p0+p1+p2+p3 + res) ----------------
// pbase: 4 bf16 split-K partials at stride 4096*1024 (p0 carries the bias).
// Residual: resf (fp32) or resb (bf16) — exactly one non-null.
__global__ __launch_bounds__(256, 4) void ln_sum_kernel(
    const bf16* __restrict__ pbase, const float* __restrict__ resf,
    const bf16* __restrict__ resb, const float* __restrict__ gw, const float* __restrict__ bw,
    float* __restrict__ y, bf16* __restrict__ ybf) {
    const int row = blockIdx.x;
    const int tid = threadIdx.x;
    const size_t base = (size_t)row * 1024 + tid * 4;
    const size_t PS = (size_t)4096 * 1024;

    float4 v = {0.f, 0.f, 0.f, 0.f};
#pragma unroll
    for (int z = 0; z < 4; ++z) {
        const bf16x4 a = *(const bf16x4*)(pbase + z * PS + base);
        v.x += bf2f(a[0]);
        v.y += bf2f(a[1]);
        v.z += bf2f(a[2]);
        v.w += bf2f(a[3]);
    }
    if (resf) {
        const float4 xr = ((const float4*)(resf + (size_t)row * 1024))[tid];
        v.x += xr.x; v.y += xr.y; v.z += xr.z; v.w += xr.w;
    } else {
        const bf16x4 xr = *(const bf16x4*)(resb + base);
        v.x += bf2f(xr[0]); v.y += bf2f(xr[1]); v.z += bf2f(xr[2]); v.w += bf2f(xr[3]);
    }

    float s = v.x + v.y + v.z + v.w;
    float s2 = v.x * v.x + v.y * v.y + v.z * v.z + v.w * v.w;
#pragma unroll
    for (int d = 1; d < 64; d <<= 1) {
        s += __shfl_xor(s, d);
        s2 += __shfl_xor(s2, d);
    }
    __shared__ float red[8];
    const int wid = tid >> 6, lane = tid & 63;
    if (lane == 0) { red[wid] = s; red[4 + wid] = s2; }
    __syncthreads();
    s = red[0] + red[1] + red[2] + red[3];
    s2 = red[4] + red[5] + red[6] + red[7];
    const float mu = s * (1.f / 1024.f);
    const float var = s2 * (1.f / 1024.f) - mu * mu;
    const float rstd = rsqrtf(var + 1e-5f);
    const float4 gv = ((const float4*)gw)[tid];
    const float4 bv = ((const float4*)bw)[tid];
    float4 out;
    out.x = (v.x - mu) * rstd * gv.x + bv.x;
    out.y = (v.y - mu) * rstd * gv.y + bv.y;
    out.z = (v.z - mu) * rstd * gv.z + bv.z;
    out.w = (v.w - mu) * rstd * gv.w + bv.w;
    if (y) ((float4*)(y + (size_t)row * 1024))[tid] = out;
    if (ybf) {
        bf16* yb = ybf + base;
        yb[0] = bf16_rn(out.x);
        yb[1] = bf16_rn(out.y);
        yb[2] = bf16_rn(out.z);
        yb[3] = bf16_rn(out.w);
    }
}

// ---------------- fused fp32 -> bf16 for all 7 inputs (one launch) ----------------
// f4-cumulative segment bounds (src, inproj_w, outw, w1, w2, memk, memv):
//   1048576, 1835008, 2097152, 3145728, 4194304, 4202496, 4210688 (= 16448*256 exactly)
__global__ void cvt_all_kernel(const float* __restrict__ s0, const float* __restrict__ s1,
                               const float* __restrict__ s2, const float* __restrict__ s3,
                               const float* __restrict__ s4, const float* __restrict__ s5,
                               const float* __restrict__ s6, bf16* __restrict__ d0,
                               bf16* __restrict__ d1, bf16* __restrict__ d2, bf16* __restrict__ d3,
                               bf16* __restrict__ d4, bf16* __restrict__ d5, bf16* __restrict__ d6) {
    int i = blockIdx.x * 256 + threadIdx.x;
    const float* in;
    bf16* out;
    float scale = 1.f;
    if (i < 1048576) {
        in = s0; out = d0;
    } else if (i < 1835008) {
        in = s1; out = d1; i -= 1048576;
    } else if (i < 2097152) {
        in = s2; out = d2; i -= 1835008;
    } else if (i < 3145728) {
        in = s3; out = d3; i -= 2097152;
    } else if (i < 4194304) {
        in = s4; out = d4; i -= 3145728;
    } else if (i < 4202496) {
        in = s5; out = d5; i -= 4194304; scale = 8.f;  // memk * d^0.5 (log2e rides on q)
    } else {
        in = s6; out = d6; i -= 4202496; scale = 5.656854249492381f;  // memv * M^0.5
    }
    const float4 v = ((const float4*)in)[i];
    bf16* op = out + (size_t)i * 4;
    op[0] = bf16_rn(v.x * scale);
    op[1] = bf16_rn(v.y * scale);
    op[2] = bf16_rn(v.z * scale);
    op[3] = bf16_rn(v.w * scale);
}

extern "C" void kernel_launch(void* const* d_in, const int* in_sizes, int n_in, void* d_out,
                              int out_size, void* d_ws, size_t ws_size, hipStream_t stream) {
    const float* src = (const float*)d_in[0];
    const float* inproj_w = (const float*)d_in[1];
    const float* inproj_b = (const float*)d_in[2];
    const float* outw = (const float*)d_in[3];
    const float* outb = (const float*)d_in[4];
    const float* memk = (const float*)d_in[5];
    const float* memv = (const float*)d_in[6];
    const float* w1 = (const float*)d_in[7];
    const float* b1 = (const float*)d_in[8];
    const float* w2 = (const float*)d_in[9];
    const float* b2 = (const float*)d_in[10];
    const float* ln1g = (const float*)d_in[11];
    const float* ln1b = (const float*)d_in[12];
    const float* ln2g = (const float*)d_in[13];
    const float* ln2b = (const float*)d_in[14];

    char* ws = (char*)d_ws;
    const size_t MB = 1024 * 1024;
    // Live-range plan (ws <= 97 MB):
    //   0..24   weights bf16 (inproj 6 | outw 2 | w1 8 | w2 8)
    //   24..25  mk_bf, mv_bf
    //   25..33  src_bf -> ctx (attn out) -> x_bf (ln1 out)
    //   33..65  qkv (gemm1 out) -> gemm2 partials (qkv dead) -> h (gemm3 out)
    //   65..97  vt (8.5MB, transpose_v -> attn) -> gemm4 partials (vt dead)
    bf16* w_inproj_bf = (bf16*)(ws + 0);
    bf16* w_out_bf = (bf16*)(ws + 6 * MB);
    bf16* w1_bf = (bf16*)(ws + 8 * MB);
    bf16* w2_bf = (bf16*)(ws + 16 * MB);
    bf16* mk_bf = (bf16*)(ws + 24 * MB);
    bf16* mv_bf = (bf16*)(ws + 24 * MB + 65536);
    bf16* src_bf = (bf16*)(ws + 25 * MB);
    bf16* ctx_bf = src_bf;     // attn out (src_bf dead after gemm1)
    bf16* x_bf = src_bf;       // ln1 out (ctx dead after gemm2)
    bf16* qkv_bf = (bf16*)(ws + 33 * MB);
    bf16* g2p = qkv_bf;        // gemm2 partials 4x8MB (qkv dead after attn)
    bf16* h_bf = qkv_bf;       // gemm3 out (partials dead after ln_sum1)
    bf16* vt_bf = (bf16*)(ws + 65 * MB);
    bf16* g4p = vt_bf;         // gemm4 partials 4x8MB (vt dead after attn)
    float* outp = (float*)d_out;

    // one fused conversion launch (16448 * 256 threads == total f4 count exactly)
    cvt_all_kernel<<<dim3(16448), dim3(256), 0, stream>>>(
        src, inproj_w, outw, w1, w2, memk, memv,
        src_bf, w_inproj_bf, w_out_bf, w1_bf, w2_bf, mk_bf, mv_bf);

    // qkv = src @ in_proj_w^T + b  (q scaled by d^-0.5*log2e)
    gemm_bt<0><<<dim3(3072 / 128, 4096 / 128), 256, 0, stream>>>(
        src_bf, w_inproj_bf, inproj_b, qkv_bf, 4096, 3072, 1024, 1024);
    // VT = V^T (incl. mem tokens)
    transpose_v<<<dim3(33, 16, 2), 256, 0, stream>>>(qkv_bf, mv_bf, vt_bf);
    // ctx = softmax(q k^T) v    (grid: x=head for XCD L2 locality; 512 blocks)
    attn_kernel<<<dim3(16, 16, 2), 256, 0, stream>>>(qkv_bf, mk_bf, vt_bf, ctx_bf);
    // gemm2 split-K x4: partials = ctx @ out_w^T (+out_b on z=0), K=256 each
    gemm_bt<3><<<dim3(1024 / 128, 4096 / 128, 4), 256, 0, stream>>>(
        ctx_bf, w_out_bf, outb, g2p, 4096, 1024, 256, 1024);
    // x = LN1(p0..p3 + src)  -> bf16 only
    ln_sum_kernel<<<dim3(4096), 256, 0, stream>>>(g2p, src, nullptr, ln1g, ln1b, nullptr, x_bf);
    // h = relu(x @ w1^T + b1)
    gemm_bt<2><<<dim3(4096 / 128, 4096 / 128), 256, 0, stream>>>(
        x_bf, w1_bf, b1, h_bf, 4096, 4096, 1024, 1024);
    // gemm4 split-K x4: partials = h @ w2^T (+b2 on z=0), K=1024 each
    gemm_bt<3><<<dim3(1024 / 128, 4096 / 128, 4), 256, 0, stream>>>(
        h_bf, w2_bf, b2, g4p, 4096, 1024, 1024, 4096);
    // out = LN2(p0..p3 + x)
    ln_sum_kernel<<<dim3(4096), 256, 0, stream>>>(g4p, nullptr, x_bf, ln2g, ln2b, outp, nullptr);
}